// Round 4
// baseline (193.914 us; speedup 1.0000x reference)
//
#include <hip/hip_runtime.h>
#include <hip/hip_bf16.h>

typedef __attribute__((ext_vector_type(8))) short bf16x8;
typedef __attribute__((ext_vector_type(4))) float f32x4;
typedef unsigned short u16;

__device__ __forceinline__ u16 f2bf(float f) {
  unsigned int u = __builtin_bit_cast(unsigned int, f);
  u += 0x7fffu + ((u >> 16) & 1u);
  return (u16)(u >> 16);
}
__device__ __forceinline__ float bf2f(unsigned int h) {
  unsigned int u = h << 16;
  return __builtin_bit_cast(float, u);
}

__device__ __forceinline__ void gload_lds16(const void* g, void* l) {
  __builtin_amdgcn_global_load_lds(
      (const __attribute__((address_space(1))) void*)g,
      (__attribute__((address_space(3))) void*)l, 16, 0, 0);
}

// ---------------------------------------------------------------------------
// K-half-slot ring NT GEMM.  C[m][n] = sum_k A[m][k]*Bt[n][k], BN=256.
// 512 thr = 8 waves (2 wr x 4 wc), per-wave (BM/2) x 64.
// Slot = one K=32 slice of A[BM][32] + B[256][32] in LDS; ring of 4 slots
// (BM=256: 32 KB/slot -> 128 KB; BM=128: 24 KB -> 96 KB). Phase s consumes
// slot s (32|16 MFMA), stages slot s+3 (SL gloads), counted vmcnt(2*SL)
// keeps 2 slots in flight (never 0 until tail). 16B-block swizzle
// cb ^= (row>>1)&3 on reads, pre-applied to staging source (0-conflict,
// verified r1-r3).
// EPI 0: fused QKV proj (Q:*1/32+bq, K:+bk, V:+bv transposed to Vt)
// EPI 2: bf16 row-major (scores)    EPI 3: f32 row-major (final out)
// ---------------------------------------------------------------------------
template <int BM, int EPI>
__global__ __launch_bounds__(512, 2) void gemmk(
    const u16* __restrict__ Abase, const u16* __restrict__ Btbase,
    const float* __restrict__ bq, const float* __restrict__ bk,
    const float* __restrict__ bv, void* __restrict__ out0,
    void* __restrict__ out1, void* __restrict__ out2, int Kd, int ldc,
    long long sAz, long long sBz, long long sCz) {
  constexpr int ASZ = BM * 32 * 2;    // A slot bytes (8192 | 16384)
  constexpr int BSZ = 256 * 32 * 2;   // 16384
  constexpr int SLOT = ASZ + BSZ;
  constexpr int AL = BM / 128;        // A gloads/thread/slot (1 | 2)
  constexpr int SL = AL + 2;          // gloads/thread/slot total (3 | 4)
  constexpr int MF = BM / 32;         // m-frags per wave (4 | 8)
  __shared__ char lds[4 * SLOT];

  const int tid = threadIdx.x;
  const int w = tid >> 6, l = tid & 63;
  const int wr = w >> 2, wc = w & 3;
  const int lq = l >> 4, lr = l & 15;
  const int bm = blockIdx.y * BM, bn = blockIdx.x * 256;
  const int z = blockIdx.z;
  const u16* A = Abase + (size_t)z * sAz;
  const u16* Bt = Btbase + (size_t)z * sBz;
  const int NS = Kd >> 5;  // total K-half slots

  // staging source: dest slot-local byte tid*16 (+8192 per extra row-block);
  // source 16B col-block pre-swizzled so linear LDS dest + swizzled read match
  const int sr = tid >> 2;
  const int scb = (tid & 3) ^ ((sr >> 1) & 3);
  const u16* gA = A + (size_t)(bm + sr) * Kd + scb * 8;
  const u16* gA2 = gA + (size_t)128 * Kd;
  const u16* gB = Bt + (size_t)(bn + sr) * Kd + scb * 8;
  const u16* gB2 = gB + (size_t)128 * Kd;

  auto stage = [&](int s) {  // stage slot s (k offset = s*32)
    const int ko = s * 32;
    char* d = lds + (s & 3) * SLOT + tid * 16;
    gload_lds16(gA + ko, d);
    if constexpr (AL == 2) gload_lds16(gA2 + ko, d + 8192);
    gload_lds16(gB + ko, d + ASZ);
    gload_lds16(gB2 + ko, d + ASZ + 8192);
  };

  const int rowA = wr * (BM / 2) + lr;
  const int rowB = wc * 64 + lr;
  const int offA = rowA * 64 + (((lq ^ (rowA >> 1)) & 3) << 4);
  const int offB = ASZ + rowB * 64 + (((lq ^ (rowB >> 1)) & 3) << 4);

  f32x4 acc[MF][4] = {};

  // prologue: stage slots 0,1,2; need slot 0 landed (allow 2 slots in flight)
  stage(0);
  stage(1);
  stage(2);
  asm volatile("s_waitcnt vmcnt(%0)" ::"n"(2 * SL) : "memory");
  __builtin_amdgcn_s_barrier();

  for (int s = 0; s < NS; ++s) {
    const char* base = lds + (s & 3) * SLOT;
    bf16x8 aR[MF], bR[4];
#pragma unroll
    for (int mi = 0; mi < MF; ++mi)
      aR[mi] = *(const bf16x8*)(base + offA + mi * 1024);
#pragma unroll
    for (int ni = 0; ni < 4; ++ni)
      bR[ni] = *(const bf16x8*)(base + offB + ni * 1024);
    if (s + 3 < NS) stage(s + 3);
    asm volatile("s_waitcnt lgkmcnt(%0)" ::"n"(MF) : "memory");
    __builtin_amdgcn_s_barrier();
    asm volatile("s_waitcnt lgkmcnt(0)" ::: "memory");
    __builtin_amdgcn_sched_barrier(0);
    __builtin_amdgcn_s_setprio(1);
#pragma unroll
    for (int mi = 0; mi < MF; ++mi)
#pragma unroll
      for (int ni = 0; ni < 4; ++ni)
        acc[mi][ni] = __builtin_amdgcn_mfma_f32_16x16x32_bf16(
            aR[mi], bR[ni], acc[mi][ni], 0, 0, 0);
    __builtin_amdgcn_s_setprio(0);
    // before next phase reads slot s+1: allow only slots s+2, s+3 in flight
    if (s + 3 < NS) {
      asm volatile("s_waitcnt vmcnt(%0)" ::"n"(2 * SL) : "memory");
    } else if (s + 2 < NS) {
      asm volatile("s_waitcnt vmcnt(%0)" ::"n"(SL) : "memory");
    } else if (s + 1 < NS) {
      asm volatile("s_waitcnt vmcnt(0)" ::: "memory");
    }
    __builtin_amdgcn_s_barrier();
  }

  // epilogue. C/D frag: col = lane&15, row = (lane>>4)*4 + e  [m89]
  const int r0 = bm + wr * (BM / 2) + lq * 4;
  const int c0 = bn + wc * 64;
  if constexpr (EPI == 0) {
    const int mat = bn >> 10;  // uniform per block (256 | 1024)
    const float sc = (mat == 0) ? 0.03125f : 1.0f;
    const float* bias = (mat == 0) ? bq : (mat == 1 ? bk : bv);
    u16* Q = (u16*)out0;
    u16* K = (u16*)out1;
    u16* V = (u16*)out2;
#pragma unroll
    for (int nf = 0; nf < 4; ++nf) {
      const int oc = (c0 & 1023) + nf * 16 + lr;
      const float bb = bias[oc];
      if (mat < 2) {
        u16* dst = (mat == 0) ? Q : K;
#pragma unroll
        for (int mi = 0; mi < MF; ++mi) {
          const int row = r0 + mi * 16;
#pragma unroll
          for (int e = 0; e < 4; ++e)
            dst[(size_t)(row + e) * 1024 + oc] =
                f2bf((acc[mi][nf][e] + bb) * sc);
        }
      } else {
#pragma unroll
        for (int mi = 0; mi < MF; ++mi) {
          const int row = r0 + mi * 16;
          const int bz = row >> 11, sdx = row & 2047;
          ushort4 pk;
          pk.x = f2bf(acc[mi][nf][0] + bb);
          pk.y = f2bf(acc[mi][nf][1] + bb);
          pk.z = f2bf(acc[mi][nf][2] + bb);
          pk.w = f2bf(acc[mi][nf][3] + bb);
          *(ushort4*)&V[((size_t)bz * 1024 + oc) * 2048 + sdx] = pk;
        }
      }
    }
  } else if constexpr (EPI == 2) {
    u16* C = (u16*)out0 + (size_t)z * sCz;
#pragma unroll
    for (int nf = 0; nf < 4; ++nf) {
      const int col = c0 + nf * 16 + lr;
#pragma unroll
      for (int mi = 0; mi < MF; ++mi) {
        const int row = r0 + mi * 16;
#pragma unroll
        for (int e = 0; e < 4; ++e)
          C[(size_t)(row + e) * ldc + col] = f2bf(acc[mi][nf][e]);
      }
    }
  } else {
    float* C = (float*)out0 + (size_t)z * sCz;
#pragma unroll
    for (int nf = 0; nf < 4; ++nf) {
      const int col = c0 + nf * 16 + lr;
#pragma unroll
      for (int mi = 0; mi < MF; ++mi) {
        const int row = r0 + mi * 16;
#pragma unroll
        for (int e = 0; e < 4; ++e)
          C[(size_t)(row + e) * ldc + col] = acc[mi][nf][e];
      }
    }
  }
}

// ---------------------------------------------------------------------------
__global__ __launch_bounds__(256) void cvt_x(const float* __restrict__ in,
                                             u16* __restrict__ out) {
  const int i = blockIdx.x * 256 + threadIdx.x;
  const float4 v = ((const float4*)in)[i];
  ushort4 o;
  o.x = f2bf(v.x);
  o.y = f2bf(v.y);
  o.z = f2bf(v.z);
  o.w = f2bf(v.w);
  ((ushort4*)out)[i] = o;
}

// W [1024 in][1024 out] f32 -> Wt [1024 out][1024 in] bf16, z selects q/k/v
__global__ void cvt_wt(const float* __restrict__ Wq,
                       const float* __restrict__ Wk,
                       const float* __restrict__ Wv, u16* __restrict__ Wt) {
  __shared__ float s[32][33];
  const float* W = blockIdx.z == 0 ? Wq : (blockIdx.z == 1 ? Wk : Wv);
  u16* O = Wt + (size_t)blockIdx.z * 1048576;
  const int k0 = blockIdx.y * 32, n0 = blockIdx.x * 32;
  s[threadIdx.y][threadIdx.x] =
      W[(size_t)(k0 + threadIdx.y) * 1024 + n0 + threadIdx.x];
  __syncthreads();
  O[(size_t)(n0 + threadIdx.y) * 1024 + k0 + threadIdx.x] =
      f2bf(s[threadIdx.x][threadIdx.y]);
}

// in-place row softmax over bf16 [4][2048][2048]; one block per row
__global__ __launch_bounds__(256) void softmax_rows(u16* __restrict__ SP) {
  const size_t base = ((size_t)blockIdx.y * 2048 + blockIdx.x) * 2048;
  u16* p = SP + base;
  const int t = threadIdx.x;
  __shared__ float red[4];

  uint4 u = ((const uint4*)p)[t];  // 8 bf16 per thread
  unsigned int uu[4] = {u.x, u.y, u.z, u.w};
  float f[8];
#pragma unroll
  for (int j = 0; j < 4; ++j) {
    f[2 * j] = bf2f(uu[j] & 0xffffu);
    f[2 * j + 1] = __builtin_bit_cast(float, uu[j] & 0xffff0000u);
  }
  float mx = f[0];
#pragma unroll
  for (int i = 1; i < 8; ++i) mx = fmaxf(mx, f[i]);
#pragma unroll
  for (int o = 32; o; o >>= 1) mx = fmaxf(mx, __shfl_xor(mx, o, 64));
  if ((t & 63) == 0) red[t >> 6] = mx;
  __syncthreads();
  mx = fmaxf(fmaxf(red[0], red[1]), fmaxf(red[2], red[3]));
  __syncthreads();

  float e[8];
  float sum = 0.f;
#pragma unroll
  for (int i = 0; i < 8; ++i) {
    e[i] = __expf(f[i] - mx);
    sum += e[i];
  }
#pragma unroll
  for (int o = 32; o; o >>= 1) sum += __shfl_xor(sum, o, 64);
  if ((t & 63) == 0) red[t >> 6] = sum;
  __syncthreads();
  sum = red[0] + red[1] + red[2] + red[3];
  const float inv = 1.0f / sum;

  uint4 ov;
  unsigned int w0[4];
#pragma unroll
  for (int j = 0; j < 4; ++j) {
    unsigned int lo = f2bf(e[2 * j] * inv);
    unsigned int hi = f2bf(e[2 * j + 1] * inv);
    w0[j] = lo | (hi << 16);
  }
  ov.x = w0[0];
  ov.y = w0[1];
  ov.z = w0[2];
  ov.w = w0[3];
  ((uint4*)p)[t] = ov;
}

// ---------------------------------------------------------------------------
extern "C" void kernel_launch(void* const* d_in, const int* in_sizes, int n_in,
                              void* d_out, int out_size, void* d_ws,
                              size_t ws_size, hipStream_t stream) {
  const float* x = (const float*)d_in[0];
  const float* Wq = (const float*)d_in[1];
  const float* bq = (const float*)d_in[2];
  const float* Wk = (const float*)d_in[3];
  const float* bk = (const float*)d_in[4];
  const float* Wv = (const float*)d_in[5];
  const float* bv = (const float*)d_in[6];
  float* out = (float*)d_out;
  char* ws = (char*)d_ws;

  u16* xb = (u16*)ws;                    // 16 MiB [8192][1024]
  u16* Wt = (u16*)(ws + 16777216);       // 6 MiB  [3072][1024]
  u16* Qb = (u16*)(ws + 23068672);       // 16 MiB [8192][1024]
  u16* Kb = Qb + 8388608;                // 16 MiB
  u16* Vt = Kb + 8388608;                // 16 MiB [4][1024][2048]
  u16* SP = Vt + 8388608;                // 32 MiB [4][2048][2048]

  // 1) dtype prep
  cvt_x<<<8192, 256, 0, stream>>>(x, xb);
  cvt_wt<<<dim3(32, 32, 3), dim3(32, 32), 0, stream>>>(Wq, Wk, Wv, Wt);

  // 2) fused QKV projection (N=3072; Q scaled 1/32 in epilogue)
  gemmk<256, 0><<<dim3(12, 32, 1), 512, 0, stream>>>(
      xb, Wt, bq, bk, bv, Qb, Kb, Vt, 1024, 0, 0, 0, 0);

  // 3) scores = Qs . K^T  (bf16 out, per batch)
  gemmk<256, 2><<<dim3(8, 8, 4), 512, 0, stream>>>(
      Qb, Kb, nullptr, nullptr, nullptr, SP, nullptr, nullptr, 1024, 2048,
      2097152LL, 2097152LL, 4194304LL);

  // 4) softmax in place
  softmax_rows<<<dim3(2048, 4), 256, 0, stream>>>(SP);

  // 5) out = P . V   (A = P [2048][2048], Bt = Vt [1024][2048])
  gemmk<128, 3><<<dim3(4, 16, 4), 512, 0, stream>>>(
      SP, Vt, nullptr, nullptr, nullptr, out, nullptr, nullptr, 2048, 1024,
      4194304LL, 2097152LL, 2097152LL);
}

// Round 5
// 179.291 us; speedup vs baseline: 1.0816x; 1.0816x over previous
//
#include <hip/hip_runtime.h>
#include <hip/hip_bf16.h>

typedef __attribute__((ext_vector_type(8))) short bf16x8;
typedef __attribute__((ext_vector_type(4))) float f32x4;
typedef unsigned short u16;

__device__ __forceinline__ u16 f2bf(float f) {
  unsigned int u = __builtin_bit_cast(unsigned int, f);
  u += 0x7fffu + ((u >> 16) & 1u);
  return (u16)(u >> 16);
}
__device__ __forceinline__ float bf2f(unsigned int h) {
  unsigned int u = h << 16;
  return __builtin_bit_cast(float, u);
}

__device__ __forceinline__ void gload_lds16(const void* g, void* l) {
  __builtin_amdgcn_global_load_lds(
      (const __attribute__((address_space(1))) void*)g,
      (__attribute__((address_space(3))) void*)l, 16, 0, 0);
}

#define VMC(N) asm volatile("s_waitcnt vmcnt(%0)" ::"n"(N) : "memory")

// ---------------------------------------------------------------------------
// 8-phase NT GEMM, m201-faithful. C[m][n] = sum_k A[m][k]*Bt[n][k]. BN=256.
// 512 thr = 8 waves (2 wr x 4 wc). Per-wave output is INTERLEAVED stripes:
// rows wr*(BM/4)+mq*(BM/2)+mf*16, cols wc*32+nq*128+nf*16 — so phase (mq,nq)
// touches exactly A-half mq and B-half nq.
// K-tile=64 rows x 128B LDS rows; dbuf; 4 phases/tile = quadrants
// (0,0),(0,1),(1,1),(1,0); B-half regs live whole tile (reads 12/4/8/0).
// One half-tile staged per phase, slot order per tile t (for t+1):
//   q0:B0 q1:B1 q2:A1 q3:A0(t+2) -> consumption lags all >=4 slots.
// Per-phase counted vmcnt BEFORE reads (never 0); cross-wave safety via
// barriers + every wave's phase(p-1) vmcnt covering slots <= p-4.
// LDS swizzle: 16B-block ^= (row&7) within 128B row (bank-rotation-free
// stride); staging source pre-swizzled, dest linear (rule 21).
// EPI 0: fused QKV proj (Q:*1/32+bq, K:+bk, V:+bv transposed to Vt)
// EPI 2: bf16 row-major (scores)    EPI 3: f32 row-major (final out)
// ---------------------------------------------------------------------------
template <int BM, int EPI>
__global__ __launch_bounds__(512, 2) void gemm8p(
    const u16* __restrict__ Abase, const u16* __restrict__ Btbase,
    const float* __restrict__ bq, const float* __restrict__ bk,
    const float* __restrict__ bv, void* __restrict__ out0,
    void* __restrict__ out1, void* __restrict__ out2, int Kd, int ldc,
    long long sAz, long long sBz, long long sCz) {
  constexpr int AHALF = BM * 64;   // bytes: (BM/2) rows x 128B
  constexpr int BHALF = 16384;     // 128 rows x 128B
  constexpr int BUFSZ = 2 * AHALF + 2 * BHALF;
  constexpr int AU_ = AHALF / 8192;  // gloads/thread per A half (1|2)
  constexpr int MF = BM / 64;        // m-frags per quadrant (2|4)
  __shared__ char lds[2 * BUFSZ];

  const int tid = threadIdx.x;
  const int w = tid >> 6, l = tid & 63;
  const int wr = w >> 2, wc = w & 3;
  const int lq = l >> 4, lr = l & 15;
  const int bm = blockIdx.y * BM, bn = blockIdx.x * 256;
  const int z = blockIdx.z;
  const u16* A = Abase + (size_t)z * sAz;
  const u16* Bt = Btbase + (size_t)z * sBz;
  const int NT = Kd >> 6;

  // ---- staging pointers (source pre-swizzled; dest linear tid*16) ----
  // dest row R = u*64 + (tid>>3); k-block kb = tid&7; src kb' = kb ^ (R&7)
  const int kbp = ((tid & 7) ^ ((tid >> 3) & 7)) * 8;  // element offset
  const int drow = tid >> 3;
  const u16* gAr[2][AU_];
  const u16* gBr[2][2];
#pragma unroll
  for (int h = 0; h < 2; ++h) {
#pragma unroll
    for (int u = 0; u < AU_; ++u)
      gAr[h][u] =
          A + (size_t)(bm + h * (BM / 2) + u * 64 + drow) * Kd + kbp;
#pragma unroll
    for (int u = 0; u < 2; ++u)
      gBr[h][u] = Bt + (size_t)(bn + h * 128 + u * 64 + drow) * Kd + kbp;
  }

  auto stageA = [&](int buf, int h, int t) {
    char* d = lds + buf * BUFSZ + h * AHALF + tid * 16;
#pragma unroll
    for (int u = 0; u < AU_; ++u) gload_lds16(gAr[h][u] + t * 64, d + u * 8192);
  };
  auto stageB = [&](int buf, int h, int t) {
    char* d = lds + buf * BUFSZ + 2 * AHALF + h * BHALF + tid * 16;
#pragma unroll
    for (int u = 0; u < 2; ++u) gload_lds16(gBr[h][u] + t * 64, d + u * 8192);
  };

  // ---- fragment read offsets (within a half) ----
  const int rA = wr * (BM / 4) + lr;
  const int rB = wc * 32 + lr;
  int aoff[2], boff[2];
#pragma unroll
  for (int kh = 0; kh < 2; ++kh) {
    aoff[kh] = rA * 128 + (((kh * 4 + lq) ^ (rA & 7)) << 4);
    boff[kh] = rB * 128 + (((kh * 4 + lq) ^ (rB & 7)) << 4);
  }

  f32x4 acc[2][MF][2][2] = {};
  bf16x8 a[2][MF];       // current A-half frags [kh][mf]
  bf16x8 bb[2][2][2];    // B frags [nq][kh][nf], live whole tile

  // per-phase vmcnt (loads of last 2 stage slots)
  constexpr int NQ0 = (BM == 256) ? 4 : 2;
  constexpr int NQ1 = (BM == 256) ? 4 : 3;
  constexpr int NQ2 = 4;
  constexpr int NQ3 = (BM == 256) ? 4 : 3;

#define RD_A(MQ)                                                            \
  {                                                                         \
    const char* ab = lds + buf * BUFSZ + (MQ)*AHALF;                        \
    _Pragma("unroll") for (int kh = 0; kh < 2; ++kh)                        \
        _Pragma("unroll") for (int mf = 0; mf < MF; ++mf) a[kh][mf] =       \
            *(const bf16x8*)(ab + aoff[kh] + mf * 2048);                    \
  }
#define RD_B(NQ)                                                            \
  {                                                                         \
    const char* bbp = lds + buf * BUFSZ + 2 * AHALF + (NQ)*BHALF;           \
    _Pragma("unroll") for (int kh = 0; kh < 2; ++kh)                        \
        _Pragma("unroll") for (int nf = 0; nf < 2; ++nf) bb[NQ][kh][nf] =   \
            *(const bf16x8*)(bbp + boff[kh] + nf * 2048);                   \
  }
#define MMAQ(MQ, NQ)                                                        \
  {                                                                         \
    __builtin_amdgcn_s_setprio(1);                                          \
    _Pragma("unroll") for (int kh = 0; kh < 2; ++kh)                        \
        _Pragma("unroll") for (int mf = 0; mf < MF; ++mf)                   \
            _Pragma("unroll") for (int nf = 0; nf < 2; ++nf)                \
                acc[MQ][mf][NQ][nf] = __builtin_amdgcn_mfma_f32_16x16x32_bf16( \
                    a[kh][mf], bb[NQ][kh][nf], acc[MQ][mf][NQ][nf], 0, 0, 0);  \
    __builtin_amdgcn_s_setprio(0);                                          \
  }

  // prologue: slots [A0(0), B0(0), B1(0), A1(0), A0(1)]
  stageA(0, 0, 0);
  stageB(0, 0, 0);
  stageB(0, 1, 0);
  stageA(0, 1, 0);
  stageA(1, 0, 1);
  VMC(NQ0);  // allow last 2 halves {A1(0), A0(1)} in flight
  __builtin_amdgcn_s_barrier();

  for (int t = 0; t < NT; ++t) {
    const int buf = t & 1, sb = buf ^ 1;
    // ---- q0: (A0,B0); stage B0(t+1) ----
    VMC(NQ0);
    RD_A(0);
    RD_B(0);
    if (t + 1 < NT) stageB(sb, 0, t + 1);
    if constexpr (BM == 256)
      asm volatile("s_waitcnt lgkmcnt(8)" ::: "memory");
    __builtin_amdgcn_s_barrier();
    MMAQ(0, 0);
    __builtin_amdgcn_s_barrier();
    // ---- q1: (A0,B1); stage B1(t+1) ----
    VMC(NQ1);
    RD_B(1);
    if (t + 1 < NT) stageB(sb, 1, t + 1);
    __builtin_amdgcn_s_barrier();
    MMAQ(0, 1);
    __builtin_amdgcn_s_barrier();
    // ---- q2: (A1,B1); stage A1(t+1) ----
    VMC(NQ2);
    RD_A(1);
    if (t + 1 < NT) stageA(sb, 1, t + 1);
    __builtin_amdgcn_s_barrier();
    MMAQ(1, 1);
    __builtin_amdgcn_s_barrier();
    // ---- q3: (A1,B0) regs-only; stage A0(t+2) into current buf ----
    VMC(NQ3);
    if (t + 2 < NT) stageA(buf, 0, t + 2);
    __builtin_amdgcn_s_barrier();
    MMAQ(1, 0);
    __builtin_amdgcn_s_barrier();
  }

  // epilogue. C/D frag: col = lane&15, row = (lane>>4)*4 + e  [m89]
  if constexpr (EPI == 0) {
    const int mat = bn >> 10;
    const float sc = (mat == 0) ? 0.03125f : 1.0f;
    const float* bias = (mat == 0) ? bq : (mat == 1 ? bk : bv);
    u16* Q = (u16*)out0;
    u16* K = (u16*)out1;
    u16* V = (u16*)out2;
#pragma unroll
    for (int nq = 0; nq < 2; ++nq)
#pragma unroll
      for (int nf = 0; nf < 2; ++nf) {
        const int oc = ((bn + wc * 32 + nq * 128 + nf * 16 + lr) & 1023);
        const float bb2 = bias[oc];
#pragma unroll
        for (int mq = 0; mq < 2; ++mq)
#pragma unroll
          for (int mf = 0; mf < MF; ++mf) {
            const int row =
                bm + wr * (BM / 4) + mq * (BM / 2) + mf * 16 + lq * 4;
            if (mat < 2) {
              u16* dst = (mat == 0) ? Q : K;
#pragma unroll
              for (int e = 0; e < 4; ++e)
                dst[(size_t)(row + e) * 1024 + oc] =
                    f2bf((acc[mq][mf][nq][nf][e] + bb2) * sc);
            } else {
              const int bz = row >> 11, sdx = row & 2047;
              ushort4 pk;
              pk.x = f2bf(acc[mq][mf][nq][nf][0] + bb2);
              pk.y = f2bf(acc[mq][mf][nq][nf][1] + bb2);
              pk.z = f2bf(acc[mq][mf][nq][nf][2] + bb2);
              pk.w = f2bf(acc[mq][mf][nq][nf][3] + bb2);
              *(ushort4*)&V[((size_t)bz * 1024 + oc) * 2048 + sdx] = pk;
            }
          }
      }
  } else if constexpr (EPI == 2) {
    u16* C = (u16*)out0 + (size_t)z * sCz;
#pragma unroll
    for (int nq = 0; nq < 2; ++nq)
#pragma unroll
      for (int nf = 0; nf < 2; ++nf) {
        const int col = bn + wc * 32 + nq * 128 + nf * 16 + lr;
#pragma unroll
        for (int mq = 0; mq < 2; ++mq)
#pragma unroll
          for (int mf = 0; mf < MF; ++mf) {
            const int row =
                bm + wr * (BM / 4) + mq * (BM / 2) + mf * 16 + lq * 4;
#pragma unroll
            for (int e = 0; e < 4; ++e)
              C[(size_t)(row + e) * ldc + col] = f2bf(acc[mq][mf][nq][nf][e]);
          }
      }
  } else {
    float* C = (float*)out0 + (size_t)z * sCz;
#pragma unroll
    for (int nq = 0; nq < 2; ++nq)
#pragma unroll
      for (int nf = 0; nf < 2; ++nf) {
        const int col = bn + wc * 32 + nq * 128 + nf * 16 + lr;
#pragma unroll
        for (int mq = 0; mq < 2; ++mq)
#pragma unroll
          for (int mf = 0; mf < MF; ++mf) {
            const int row =
                bm + wr * (BM / 4) + mq * (BM / 2) + mf * 16 + lq * 4;
#pragma unroll
            for (int e = 0; e < 4; ++e)
              C[(size_t)(row + e) * ldc + col] = acc[mq][mf][nq][nf][e];
          }
      }
  }
#undef RD_A
#undef RD_B
#undef MMAQ
}

// ---------------------------------------------------------------------------
__global__ __launch_bounds__(256) void cvt_x(const float* __restrict__ in,
                                             u16* __restrict__ out) {
  const int i = blockIdx.x * 256 + threadIdx.x;
  const float4 v = ((const float4*)in)[i];
  ushort4 o;
  o.x = f2bf(v.x);
  o.y = f2bf(v.y);
  o.z = f2bf(v.z);
  o.w = f2bf(v.w);
  ((ushort4*)out)[i] = o;
}

// W [1024 in][1024 out] f32 -> Wt [1024 out][1024 in] bf16, z selects q/k/v
__global__ void cvt_wt(const float* __restrict__ Wq,
                       const float* __restrict__ Wk,
                       const float* __restrict__ Wv, u16* __restrict__ Wt) {
  __shared__ float s[32][33];
  const float* W = blockIdx.z == 0 ? Wq : (blockIdx.z == 1 ? Wk : Wv);
  u16* O = Wt + (size_t)blockIdx.z * 1048576;
  const int k0 = blockIdx.y * 32, n0 = blockIdx.x * 32;
  s[threadIdx.y][threadIdx.x] =
      W[(size_t)(k0 + threadIdx.y) * 1024 + n0 + threadIdx.x];
  __syncthreads();
  O[(size_t)(n0 + threadIdx.y) * 1024 + k0 + threadIdx.x] =
      f2bf(s[threadIdx.x][threadIdx.y]);
}

// in-place row softmax over bf16 [4][2048][2048]; one block per row
__global__ __launch_bounds__(256) void softmax_rows(u16* __restrict__ SP) {
  const size_t base = ((size_t)blockIdx.y * 2048 + blockIdx.x) * 2048;
  u16* p = SP + base;
  const int t = threadIdx.x;
  __shared__ float red[4];

  uint4 u = ((const uint4*)p)[t];  // 8 bf16 per thread
  unsigned int uu[4] = {u.x, u.y, u.z, u.w};
  float f[8];
#pragma unroll
  for (int j = 0; j < 4; ++j) {
    f[2 * j] = bf2f(uu[j] & 0xffffu);
    f[2 * j + 1] = __builtin_bit_cast(float, uu[j] & 0xffff0000u);
  }
  float mx = f[0];
#pragma unroll
  for (int i = 1; i < 8; ++i) mx = fmaxf(mx, f[i]);
#pragma unroll
  for (int o = 32; o; o >>= 1) mx = fmaxf(mx, __shfl_xor(mx, o, 64));
  if ((t & 63) == 0) red[t >> 6] = mx;
  __syncthreads();
  mx = fmaxf(fmaxf(red[0], red[1]), fmaxf(red[2], red[3]));
  __syncthreads();

  float e[8];
  float sum = 0.f;
#pragma unroll
  for (int i = 0; i < 8; ++i) {
    e[i] = __expf(f[i] - mx);
    sum += e[i];
  }
#pragma unroll
  for (int o = 32; o; o >>= 1) sum += __shfl_xor(sum, o, 64);
  if ((t & 63) == 0) red[t >> 6] = sum;
  __syncthreads();
  sum = red[0] + red[1] + red[2] + red[3];
  const float inv = 1.0f / sum;

  uint4 ov;
  unsigned int w0[4];
#pragma unroll
  for (int j = 0; j < 4; ++j) {
    unsigned int lo = f2bf(e[2 * j] * inv);
    unsigned int hi = f2bf(e[2 * j + 1] * inv);
    w0[j] = lo | (hi << 16);
  }
  ov.x = w0[0];
  ov.y = w0[1];
  ov.z = w0[2];
  ov.w = w0[3];
  ((uint4*)p)[t] = ov;
}

// ---------------------------------------------------------------------------
extern "C" void kernel_launch(void* const* d_in, const int* in_sizes, int n_in,
                              void* d_out, int out_size, void* d_ws,
                              size_t ws_size, hipStream_t stream) {
  const float* x = (const float*)d_in[0];
  const float* Wq = (const float*)d_in[1];
  const float* bq = (const float*)d_in[2];
  const float* Wk = (const float*)d_in[3];
  const float* bk = (const float*)d_in[4];
  const float* Wv = (const float*)d_in[5];
  const float* bv = (const float*)d_in[6];
  float* out = (float*)d_out;
  char* ws = (char*)d_ws;

  u16* xb = (u16*)ws;                    // 16 MiB [8192][1024]
  u16* Wt = (u16*)(ws + 16777216);       // 6 MiB  [3072][1024]
  u16* Qb = (u16*)(ws + 23068672);       // 16 MiB [8192][1024]
  u16* Kb = Qb + 8388608;                // 16 MiB
  u16* Vt = Kb + 8388608;                // 16 MiB [4][1024][2048]
  u16* SP = Vt + 8388608;                // 32 MiB [4][2048][2048]

  // 1) dtype prep
  cvt_x<<<8192, 256, 0, stream>>>(x, xb);
  cvt_wt<<<dim3(32, 32, 3), dim3(32, 32), 0, stream>>>(Wq, Wk, Wv, Wt);

  // 2) fused QKV projection (N=3072; Q scaled 1/32 in epilogue)
  gemm8p<256, 0><<<dim3(12, 32, 1), 512, 0, stream>>>(
      xb, Wt, bq, bk, bv, Qb, Kb, Vt, 1024, 0, 0, 0, 0);

  // 3) scores = Qs . K^T  (bf16 out, per batch)
  gemm8p<256, 2><<<dim3(8, 8, 4), 512, 0, stream>>>(
      Qb, Kb, nullptr, nullptr, nullptr, SP, nullptr, nullptr, 1024, 2048,
      2097152LL, 2097152LL, 4194304LL);

  // 4) softmax in place
  softmax_rows<<<dim3(2048, 4), 256, 0, stream>>>(SP);

  // 5) out = P . V   (A = P [2048][2048], Bt = Vt [1024][2048])
  gemm8p<128, 3><<<dim3(4, 16, 4), 512, 0, stream>>>(
      SP, Vt, nullptr, nullptr, nullptr, out, nullptr, nullptr, 2048, 1024,
      4194304LL, 2097152LL, 2097152LL);
}